// Round 9
// baseline (462.969 us; speedup 1.0000x reference)
//
#include <hip/hip_runtime.h>
#include <hip/hip_bf16.h>

// Geometry (pad=1): conv1/conv2 -> (2,16,128^3), conv3 s2 -> (2,32,64^3).
// y1/y2 voxel-interleaved [b][z][y][x][ic16] (32B/voxel). f0 channel-major.
// Round 19: conv3 stage loads full 32B/voxel ONCE (was 16B per half-pass,
// touching each 64B line twice); BN all 16ch immediately; half-1 kept
// post-BN in 9 uint4 regs, phase-2 is 9 pure ds_write_b128 (no loads/VALU).
// Removes the second 9-load L2-latency batch from the critical path.
// conv1/conv2 (r15 z-8)/gemm (KSPLIT=128) unchanged.

typedef __hip_bfloat16 bf16;
typedef __attribute__((ext_vector_type(8))) short short8;   // 8 bf16 = 4 VGPR
typedef __attribute__((ext_vector_type(4))) float f32x4;
__device__ __forceinline__ float b2f(bf16 v){ return __bfloat162float(v); }
__device__ __forceinline__ bf16 f2b(float v){ return __float2bfloat16(v); }
__device__ __forceinline__ unsigned short f2bu(float f){   // RNE
  unsigned u = __float_as_uint(f);
  return (unsigned short)((u + 0x7fff + ((u>>16)&1)) >> 16);
}
__device__ __forceinline__ unsigned cvtpk(float lo, float hi){  // 2xf32 -> 2xbf16 RNE
  unsigned r;
  asm("v_cvt_pk_bf16_f32 %0, %1, %2" : "=v"(r) : "v"(lo), "v"(hi));
  return r;
}

#define SP12 2097152   // 128^3
#define SP3  262144    // 64^3
#define M_TOT 686
#define TOK_OFF 0
#define AUX_OFF 87808
#define CRD_OFF 109760
#define KSPLIT 128
#define NSLAB 32

// ------------- pack conv weights to frag layout, zero-padded K --------------
// wp1: [oc16][32]  (k = tap, taps 27..31 = 0)
// wp2: [oc16][448] (k = tap*16+ic, tap 27 = 0)
// wp3: [oc32][h2][224] (k2: tap = (k2>>5)*4 + ((k2>>3)&3), ic = h*8 + (k2&7))
__global__ __launch_bounds__(256) void k_packw(const float* __restrict__ w1,
                                               const float* __restrict__ w2,
                                               const float* __restrict__ w3,
                                               unsigned short* __restrict__ wp1,
                                               unsigned short* __restrict__ wp2,
                                               unsigned short* __restrict__ wp3){
  int i = blockIdx.x*256 + threadIdx.x;   // 22016 items
  if(i < 512){
    int oc = i>>5, k = i&31;
    float v = (k<27)? w1[oc*27+k] : 0.f;
    wp1[i] = f2bu(v);
  } else if(i < 7680){
    int j = i - 512;
    int oc = j/448, k = j - oc*448;
    int tap = k>>4, ic = k&15;
    float v = (tap<27)? w2[(oc*16+ic)*27+tap] : 0.f;
    wp2[oc*448+k] = f2bu(v);
  } else if(i < 22016){
    int j = i - 7680;
    int oc = j/448, r = j - oc*448;
    int h = r/224, k2 = r - h*224;
    int tap = (k2>>5)*4 + ((k2>>3)&3);
    int ic = h*8 + (k2&7);
    float v = (tap<27)? w3[(oc*16+ic)*27+tap] : 0.f;
    wp3[oc*448 + h*224 + k2] = f2bu(v);
  }
}

// ---------------- conv1 (MFMA): (2,1,128^3)->(2,16,128^3), BN1 stats fused --
#define C1P 88
__global__ __launch_bounds__(256) void k_conv1(const float* __restrict__ x,
                                               const unsigned short* __restrict__ wp1,
                                               unsigned short* __restrict__ y1u,
                                               float* __restrict__ psum){
  __shared__ unsigned short in_l[6*6*C1P];   // 6336 B
  int t = threadIdx.x;
  int bx = blockIdx.x;
  int xt = bx&1, yt = (bx>>1)&31, zt = (bx>>6)&31, b = bx>>11;
  int x0 = xt*64, y0 = yt*4, z0 = zt*4;

  for(int i=t; i<648; i+=256){
    int c = i%18; int row = i/18; int yy = row%6; int zz = row/6;
    int gz = z0-1+zz, gy = y0-1+yy;
    bool rowok = ((unsigned)gz<128u) && ((unsigned)gy<128u);
    int gx4 = x0-4+c*4;
    const float* rp = x + (size_t)b*SP12 + (rowok? ((gz<<14)+(gy<<7)) : 0);
    float v0,v1,v2,v3;
    if(rowok && gx4>=0 && gx4<=124){
      float4 v = *(const float4*)(rp + gx4);
      v0=v.x; v1=v.y; v2=v.z; v3=v.w;
    } else {
      float vv[4];
#pragma unroll
      for(int e=0;e<4;e++){
        int gx = gx4+e; bool ok = rowok && ((unsigned)gx<128u);
        float val = rp[ok? gx : 0];
        vv[e] = ok? val : 0.f;
      }
      v0=vv[0]; v1=vv[1]; v2=vv[2]; v3=vv[3];
    }
    uint2 p;
    p.x = cvtpk(v0,v1);
    p.y = cvtpk(v2,v3);
    *(uint2*)&in_l[row*C1P + c*4] = p;
  }
  __syncthreads();

  int lane = t&63, wv = t>>6;
  int m = lane&15, q = lane>>4;
  short8 wfr = *(const short8*)(wp1 + m*32 + q*8);
  int toff[8];
#pragma unroll
  for(int j=0;j<8;j++){
    int tap = q*8+j; if(tap>26) tap=26;
    int dz = tap/9; int rr = tap-dz*9; int dy = rr/3; int dx = rr-dy*3;
    toff[j] = (dz*6+dy)*C1P + dx + 3 + m;
  }
  float s4[4]={0.f,0.f,0.f,0.f}, q4[4]={0.f,0.f,0.f,0.f};
#pragma unroll
  for(int yi=0; yi<4; yi++){
#pragma unroll
    for(int mg=0; mg<4; mg++){
      int base = (wv*6+yi)*C1P + mg*16;
      short8 vf;
#pragma unroll
      for(int j=0;j<8;j++) vf[j] = (short)in_l[base + toff[j]];
      f32x4 acc = (f32x4){0.f,0.f,0.f,0.f};
      acc = __builtin_amdgcn_mfma_f32_16x16x32_bf16(wfr, vf, acc, 0,0,0);
      int gz = z0+wv, gy = y0+yi, gxv = x0 + mg*16 + m;
      size_t vbase = (size_t)((b<<21)|(gz<<14)|(gy<<7)|gxv);
      uint2 pw; pw.x = cvtpk(acc[0],acc[1]); pw.y = cvtpk(acc[2],acc[3]);
      *(uint2*)(y1u + vbase*16 + q*4) = pw;
#pragma unroll
      for(int reg=0; reg<4; reg++){
        float v = acc[reg];
        s4[reg] += v; q4[reg] += v*v;
      }
    }
  }
#pragma unroll
  for(int off=1; off<16; off<<=1){
#pragma unroll
    for(int rg=0;rg<4;rg++){ s4[rg] += __shfl_xor(s4[rg],off); q4[rg] += __shfl_xor(q4[rg],off); }
  }
  __syncthreads();
  float* red = (float*)in_l;
  if(m==0){
#pragma unroll
    for(int rg=0;rg<4;rg++){ red[wv*32 + q*4+rg] = s4[rg]; red[wv*32+16 + q*4+rg] = q4[rg]; }
  }
  __syncthreads();
  if(t<32){
    float tot = red[t]+red[32+t]+red[64+t]+red[96+t];
    atomicAdd(&psum[(blockIdx.x & (NSLAB-1))*64 + t], tot);
  }
}

// ------------- scale/shift from slabbed sums --------------------------------
__global__ void k_finalize(const float* __restrict__ psum, const float* __restrict__ g,
                           const float* __restrict__ bb, float* __restrict__ scsh,
                           int C, float invN){
  int i = threadIdx.x;
  if(i<C){
    float s=0.f, q=0.f;
    for(int sl=0; sl<NSLAB; sl++){ s += psum[sl*64+i]; q += psum[sl*64+C+i]; }
    float mean = s*invN;
    float var  = q*invN - mean*mean;
    float sc = g[i]*rsqrtf(var+1e-5f);
    scsh[i]   = sc;
    scsh[C+i] = bb[i] - mean*sc;
  }
}

// ---------------- conv2 (MFMA): interleaved in/out, bn1+relu on stage -------
// r15 z-8 version: LDS-read-throughput bound (~72us LDS pipe); z-8 amortizes
// stage/epilogue best. 32B/voxel, h^sw half swizzle, fixed (xl,zz) stage map.
__global__ __launch_bounds__(256) void k_conv2(const unsigned short* __restrict__ y1u,
                                               const unsigned short* __restrict__ wp2,
                                               const float* __restrict__ scsh,
                                               unsigned short* __restrict__ y2u,
                                               float* __restrict__ psum2){
  __shared__ unsigned short tile[10*6*18*16];   // 34,560 B
  __shared__ float s_sc[16], s_sh[16];
  int t = threadIdx.x;
  if(t < 32){ float v = scsh[t]; if(t<16) s_sc[t]=v; else s_sh[t-16]=v; }
  int bx = blockIdx.x;
  int txx = bx&7, tyy=(bx>>3)&31, tzz=(bx>>8)&15, b=bx>>12;
  int x0 = txx*16, y0 = tyy*4, z0 = tzz*8;

  // ---- stage ----
  {
    int sxl = t%18, szz = t/18;
    bool sact = t < 180;
    int gx = x0 + sxl - 1, gz = z0 + szz - 1;
    bool szok = sact && ((unsigned)gx<128u) && ((unsigned)gz<128u);
    size_t srow0 = szok ? (size_t)((b<<21)|(gz<<14)|gx) : 0;
    int sw8 = ((sxl>>2)&1)*8;
    int tb = (szz*6*18 + sxl)*16;
    __syncthreads();                      // s_sc ready
    if(sact){
#pragma unroll
      for(int yy=0; yy<6; yy++){
        int gy = y0 + yy - 1;
        bool ok = szok && ((unsigned)gy < 128u);
        uint4 o0; o0.x=0;o0.y=0;o0.z=0;o0.w=0;
        uint4 o1 = o0;
        if(ok){
          const unsigned short* src = y1u + ((srow0 | ((size_t)gy<<7))<<4);
          uint4 u0 = *(const uint4*)src;
          uint4 u1 = *(const uint4*)(src+8);
          unsigned uu[8]; uu[0]=u0.x; uu[1]=u0.y; uu[2]=u0.z; uu[3]=u0.w;
          uu[4]=u1.x; uu[5]=u1.y; uu[6]=u1.z; uu[7]=u1.w;
          unsigned oo[8];
#pragma unroll
          for(int j=0;j<8;j++){
            float lo = fmaxf(__uint_as_float(uu[j]<<16)        *s_sc[2*j]   + s_sh[2*j],   0.f);
            float hi = fmaxf(__uint_as_float(uu[j]&0xffff0000u)*s_sc[2*j+1] + s_sh[2*j+1], 0.f);
            oo[j] = cvtpk(lo, hi);
          }
          o0.x=oo[0]; o0.y=oo[1]; o0.z=oo[2]; o0.w=oo[3];
          o1.x=oo[4]; o1.y=oo[5]; o1.z=oo[6]; o1.w=oo[7];
        }
        unsigned short* dst = &tile[tb + yy*288];
        *(uint4*)(dst + sw8)       = o0;   // h=0 at (0^sw)*8
        *(uint4*)(dst + (8 - sw8)) = o1;   // h=1 at (1^sw)*8
      }
    }
  }
  __syncthreads();

  // ---- compute ----
  int lane = t & 63, wid = t>>6;
  int m = lane & 15, q = lane>>4;
  int qh = q&1, qt = q>>1;
  f32x4 acc[8];
#pragma unroll
  for(int r=0;r<8;r++) acc[r] = (f32x4){0.f,0.f,0.f,0.f};
  const char* tbase = (const char*)tile + wid*6912;
  const unsigned short* wrow = wp2 + m*448 + q*8;
#pragma unroll
  for(int kp=0;kp<14;kp++){
    short8 wf = *(const short8*)(wrow + kp*32);     // A: oc=m
    int tap = kp*2 + qt; if(tap>26) tap=26;
    int dz = tap/9; int rr2 = tap - dz*9; int dy = rr2/3; int dx = rr2 - dy*3;
    int xl = m + dx;
    int abyte = ((dz*6 + dy)*18 + xl)*32 + ((qh ^ ((xl>>2)&1))*16);
    const char* ap = tbase + abyte;
#pragma unroll
    for(int r=0;r<8;r++){
      const short8 vf = *(const short8*)(ap + ((r>>2)*6 + (r&3))*576);
      acc[r] = __builtin_amdgcn_mfma_f32_16x16x32_bf16(wf, vf, acc[r], 0,0,0);
    }
  }

  // ---- epilogue: packed 8B stores + fused BN2 stats ----
  float s4[4]={0.f,0.f,0.f,0.f}, q4[4]={0.f,0.f,0.f,0.f};
#pragma unroll
  for(int r=0;r<8;r++){
    int gz = z0 + wid*2 + (r>>2), gy = y0 + (r&3);
    size_t vbase = (size_t)((b<<21)|(gz<<14)|(gy<<7)|(x0+m));
    uint2 pw; pw.x = cvtpk(acc[r][0],acc[r][1]); pw.y = cvtpk(acc[r][2],acc[r][3]);
    *(uint2*)(y2u + vbase*16 + q*4) = pw;
#pragma unroll
    for(int reg=0;reg<4;reg++){
      float v = acc[r][reg];
      s4[reg] += v; q4[reg] += v*v;
    }
  }
#pragma unroll
  for(int off=1; off<16; off<<=1){
#pragma unroll
    for(int rg=0;rg<4;rg++){ s4[rg] += __shfl_xor(s4[rg],off); q4[rg] += __shfl_xor(q4[rg],off); }
  }
  __syncthreads();
  float* red = (float*)tile;
  if(m==0){
#pragma unroll
    for(int rg=0;rg<4;rg++){ red[wid*32 + q*4+rg] = s4[rg]; red[wid*32+16 + q*4+rg] = q4[rg]; }
  }
  __syncthreads();
  if(t<32){
    float tot = red[t]+red[32+t]+red[64+t]+red[96+t];
    atomicAdd(&psum2[(blockIdx.x & (NSLAB-1))*64 + t], tot);
  }
}

// ---------------- conv3 (MFMA, stride2): interleaved in, channel-major out --
// Stage loads full 32B/voxel once; BN 16ch; half-0 -> LDS, half-1 kept
// post-BN in 9 uint4 regs; phase 2 = 9 pure ds_write_b128.
#define C3PITCH 576   // bytes per (z,y) row: 36 voxels * 16B
__global__ __launch_bounds__(256) void k_conv3(const unsigned short* __restrict__ y2u,
                                               const unsigned short* __restrict__ wp3,
                                               const float* __restrict__ scsh,
                                               bf16* __restrict__ f0,
                                               float* __restrict__ psum3){
  __shared__ unsigned short tile3[45*288];   // 25,920 B
  __shared__ float s_sc[16], s_sh[16];
  int t = threadIdx.x;
  if(t < 32){ float v = scsh[t]; if(t<16) s_sc[t]=v; else s_sh[t-16]=v; }
  int bx = blockIdx.x;
  int tx = bx&3, ty=(bx>>2)&15, tz=(bx>>6)&31, b=bx>>11;
  int x0 = tx*16, y0 = ty*4, z0 = tz*2;
  int gx0 = 2*x0-1, gy0 = 2*y0-1, gz0 = 2*z0-1;

  // stage mapping: t<165 -> (sxl 0..32, szz 0..4), loop yy 0..8
  int sxl = t%33, szz = t/33;
  bool sact = t < 165;
  int gx = gx0+sxl, gz = gz0+szz;
  bool sok = sact && (gx>=0) && (gz>=0);
  int gxc = (sact && gx>=0)? gx : 0;
  int gzc = (sact && gz>=0)? gz : 0;
  const unsigned short* sbase = y2u + (((size_t)((b<<21)|(gzc<<14)|gxc))<<4);
  int sb = (sxl<<4) ^ ((sxl&8)<<1) ^ ((sxl&16)<<1);
  char* sdst = (char*)tile3 + szz*9*C3PITCH + sb;
  unsigned ymask = 0;
#pragma unroll
  for(int yy=0;yy<9;yy++){
    if(sok && (gy0+yy)>=0) ymask |= (1u<<yy);
  }

  __syncthreads();     // s_sc ready

  int lane = t & 63, wid = t>>6;
  int m = lane & 15, q = lane>>4;
  f32x4 acc[2][2];
#pragma unroll
  for(int r=0;r<2;r++){ acc[r][0]=(f32x4){0,0,0,0}; acc[r][1]=(f32x4){0,0,0,0}; }
  const unsigned short* wr0 = wp3 + m*448      + q*8;
  const unsigned short* wr1 = wp3 + (16+m)*448 + q*8;

  // phase A: load full 32B, BN 16ch, store half-0 to LDS, keep half-1 in regs
  uint4 h1[9];
  if(sact){
#pragma unroll
    for(int yy=0;yy<9;yy++){
      int gy = gy0+yy; int gyc = gy<0?0:gy;
      const unsigned short* src = sbase + (size_t)gyc*2048;
      uint4 u0 = *(const uint4*)src;
      uint4 u1 = *(const uint4*)(src+8);
      uint4 o0; o0.x=0;o0.y=0;o0.z=0;o0.w=0;
      uint4 o1 = o0;
      if((ymask>>yy)&1){
        unsigned uu[8]; uu[0]=u0.x; uu[1]=u0.y; uu[2]=u0.z; uu[3]=u0.w;
        uu[4]=u1.x; uu[5]=u1.y; uu[6]=u1.z; uu[7]=u1.w;
        unsigned oo[8];
#pragma unroll
        for(int j=0;j<8;j++){
          float lo = fmaxf(__uint_as_float(uu[j]<<16)        *s_sc[2*j]   + s_sh[2*j],   0.f);
          float hi = fmaxf(__uint_as_float(uu[j]&0xffff0000u)*s_sc[2*j+1] + s_sh[2*j+1], 0.f);
          oo[j] = cvtpk(lo, hi);
        }
        o0.x=oo[0]; o0.y=oo[1]; o0.z=oo[2]; o0.w=oo[3];
        o1.x=oo[4]; o1.y=oo[5]; o1.z=oo[6]; o1.w=oo[7];
      }
      *(uint4*)(sdst + yy*C3PITCH) = o0;
      h1[yy] = o1;
    }
  }

  auto compute = [&](int half){
    const unsigned short* w0h = wr0 + half*224;
    const unsigned short* w1h = wr1 + half*224;
#pragma unroll
    for(int kp=0;kp<7;kp++){
      short8 bf0 = *(const short8*)(w0h + kp*32);
      short8 bf1 = *(const short8*)(w1h + kp*32);
      int tap = kp*4 + q; if(tap>26) tap=26;
      int dz = tap/9; int rr = tap - dz*9; int dy = rr/3; int dx = rr - dy*3;
      int xl = 2*m + dx;
      int sbi = (xl<<4) ^ ((xl&8)<<1) ^ ((xl&16)<<1);
#pragma unroll
      for(int rl=0;rl<2;rl++){
        int row = wid*2 + rl;
        int tz_ = 2*(row>>2) + dz;
        int ty_ = 2*(row&3) + dy;
        const short8 af = *(const short8*)((const char*)tile3 + (tz_*9+ty_)*C3PITCH + sbi);
        acc[rl][0] = __builtin_amdgcn_mfma_f32_16x16x32_bf16(af, bf0, acc[rl][0], 0,0,0);
        acc[rl][1] = __builtin_amdgcn_mfma_f32_16x16x32_bf16(af, bf1, acc[rl][1], 0,0,0);
      }
    }
  };

  __syncthreads();       // half-0 tile ready
  compute(0);
  __syncthreads();       // compute done, tile reusable
  if(sact){
#pragma unroll
    for(int yy=0;yy<9;yy++) *(uint4*)(sdst + yy*C3PITCH) = h1[yy];
  }
  __syncthreads();       // half-1 tile ready
  compute(1);

  float s0=0.f,q0=0.f,s1=0.f,q1=0.f;
#pragma unroll
  for(int rl=0;rl<2;rl++){
    int row = wid*2 + rl;
    int oz = z0 + (row>>2), oy = y0 + (row&3);
    size_t sp = (size_t)oz*4096 + oy*64 + x0 + q*4;
#pragma unroll
    for(int oct=0;oct<2;oct++){
      int oc = oct*16 + m;
      bf16* dst = f0 + (size_t)(b*32+oc)*SP3 + sp;
      f32x4 a = acc[rl][oct];
      uint2 pw; pw.x = cvtpk(a[0],a[1]); pw.y = cvtpk(a[2],a[3]);
      *(uint2*)dst = pw;
#pragma unroll
      for(int reg=0;reg<4;reg++){
        float v = a[reg];
        if(oct==0){ s0 += v; q0 += v*v; } else { s1 += v; q1 += v*v; }
      }
    }
  }
  s0 += __shfl_xor(s0,16); s0 += __shfl_xor(s0,32);
  q0 += __shfl_xor(q0,16); q0 += __shfl_xor(q0,32);
  s1 += __shfl_xor(s1,16); s1 += __shfl_xor(s1,32);
  q1 += __shfl_xor(q1,16); q1 += __shfl_xor(q1,32);
  __syncthreads();
  float* red = (float*)tile3;
  if(lane<16){
    red[wid*64+lane]    = s0; red[wid*64+16+lane] = s1;
    red[wid*64+32+lane] = q0; red[wid*64+48+lane] = q1;
  }
  __syncthreads();
  if(t<64){
    float tot = red[t]+red[64+t]+red[128+t]+red[192+t];
    atomicAdd(&psum3[(blockIdx.x & (NSLAB-1))*64 + t], tot);
  }
}

// ---------------- MFMA projection GEMM: M=686, N=160, K=131072 --------------
// KSPLIT=128: ks = c*4 + kq, each block does 16 bk-steps of 64 k. W staged
// from f32 with fused cvt. XCD swizzle: logical=(bid&7)*176+(bid>>3).
__global__ __launch_bounds__(256) void k_gemm(const bf16* __restrict__ f0,
                                              const float* __restrict__ tokw,
                                              const float* __restrict__ auxw,
                                              const float* __restrict__ scsh3,
                                              float* __restrict__ out_acc){
  __shared__ unsigned short Al[64*72];
  __shared__ unsigned short Wl[160*72];
  int bid = blockIdx.x;
  int logical = (bid & 7)*176 + (bid >> 3);   // 1408 = 8 XCDs * 176
  int ks = logical/11; int mblk = logical - ks*11;
  int M0 = mblk*64;
  int c  = ks >> 2; int kq = ks & 3;
  float sc = scsh3[c], sh = scsh3[32+c];
  int t = threadIdx.x;
  int lane = t & 63; int wid = t >> 6;
  int wm = (wid & 1)*32; int wn = (wid >> 1)*80;
  f32x4 acc[2][5];
#pragma unroll
  for(int i=0;i<2;i++)
#pragma unroll
    for(int j=0;j<5;j++) acc[i][j] = (f32x4){0.f,0.f,0.f,0.f};

  int ky_off0 = (t&7)>>1, half0 = t&1;
  int m_a = t>>3;
  int mg1 = M0 + m_a;       if(mg1>685) mg1=685;
  int mg2 = M0 + m_a + 32;  if(mg2>685) mg2=685;
  int b1 = mg1/343, r1 = mg1%343;
  int b2 = mg2/343, r2 = mg2%343;
  int sp1 = ((r1/49)*8)*4096 + (((r1/7)%7)*8)*64 + (r1%7)*8;
  int sp2 = ((r2/49)*8)*4096 + (((r2/7)%7)*8)*64 + (r2%7)*8;
  const bf16* f0c1 = f0 + (size_t)(b1*32+c)*SP3;
  const bf16* f0c2 = f0 + (size_t)(b2*32+c)*SP3;

  int wrow_n = t>>3;                 // 0..31 within p-group
  int wkoff  = (t&7)*8;              // 8 floats = 2 float4

  for(int bk=0; bk<16; bk++){
    int bk2 = kq*16 + bk;
    int kz = bk2>>2; int kyb = (bk2&3)*4;
    size_t kbase = (size_t)c*4096 + bk2*64 + wkoff;
    __syncthreads();
#pragma unroll
    for(int p=0;p<5;p++){
      int n = p*32 + wrow_n;
      const float* wsrc = (p<4) ? (tokw + (size_t)n*131072)
                                : (auxw + (size_t)(n-128)*131072);
      float4 v0 = *(const float4*)(wsrc + kbase);
      float4 v1 = *(const float4*)(wsrc + kbase + 4);
      uint4 pw;
      pw.x = cvtpk(v0.x, v0.y); pw.y = cvtpk(v0.z, v0.w);
      pw.z = cvtpk(v1.x, v1.y); pw.w = cvtpk(v1.z, v1.w);
      *(uint4*)&Wl[n*72 + wkoff] = pw;
    }
    {
      int ky = kyb + ky_off0; int xo = half0*8;
      int ldso = ky_off0*16 + half0*8;
      uint4 u1 = *(const uint4*)(f0c1 + sp1 + kz*4096 + ky*64 + xo);
      uint4 u2 = *(const uint4*)(f0c2 + sp2 + kz*4096 + ky*64 + xo);
      unsigned uu[8]; uu[0]=u1.x; uu[1]=u1.y; uu[2]=u1.z; uu[3]=u1.w;
      uu[4]=u2.x; uu[5]=u2.y; uu[6]=u2.z; uu[7]=u2.w;
      unsigned outw[8];
#pragma unroll
      for(int qq=0;qq<8;qq++){
        float lo = fmaxf(__uint_as_float(uu[qq]<<16)*sc + sh, 0.f);
        float hi = fmaxf(__uint_as_float(uu[qq]&0xffff0000u)*sc + sh, 0.f);
        outw[qq] = cvtpk(lo, hi);
      }
      uint4 w1; w1.x=outw[0]; w1.y=outw[1]; w1.z=outw[2]; w1.w=outw[3];
      uint4 w2; w2.x=outw[4]; w2.y=outw[5]; w2.z=outw[6]; w2.w=outw[7];
      *(uint4*)&Al[m_a*72 + ldso] = w1;
      *(uint4*)&Al[(m_a+32)*72 + ldso] = w2;
    }
    __syncthreads();
#pragma unroll
    for(int kstep=0;kstep<2;kstep++){
      int ko = kstep*32 + (lane>>4)*8;
      short8 af[2], bfr[5];
#pragma unroll
      for(int mt=0;mt<2;mt++)
        af[mt] = *(const short8*)&Al[(wm + mt*16 + (lane&15))*72 + ko];
#pragma unroll
      for(int nt=0;nt<5;nt++)
        bfr[nt] = *(const short8*)&Wl[(wn + nt*16 + (lane&15))*72 + ko];
#pragma unroll
      for(int mt=0;mt<2;mt++)
#pragma unroll
        for(int nt=0;nt<5;nt++)
          acc[mt][nt] = __builtin_amdgcn_mfma_f32_16x16x32_bf16(af[mt], bfr[nt], acc[mt][nt], 0,0,0);
    }
  }
#pragma unroll
  for(int mt=0;mt<2;mt++){
    int mb = M0 + wm + mt*16 + (lane>>4)*4;
#pragma unroll
    for(int nt=0;nt<5;nt++){
      int n = wn + nt*16 + (lane&15);
#pragma unroll
      for(int reg=0;reg<4;reg++){
        int mm = mb + reg;
        if(mm < M_TOT)
          out_acc[((size_t)ks*M_TOT + mm)*160 + n] = acc[mt][nt][reg];
      }
    }
  }
}

// ------------- reduce split-K, +bias, LN(tokens), coords, write out ---------
__global__ __launch_bounds__(256) void k_final(const float* __restrict__ out_acc,
                                               const float* __restrict__ tok_b,
                                               const float* __restrict__ aux_b,
                                               const float* __restrict__ ln_g,
                                               const float* __restrict__ ln_b,
                                               float* __restrict__ out){
  int m = blockIdx.x;            // 0..685
  int n = threadIdx.x;
  __shared__ float sA[128], sB[128];
  float sum = 0.f;
  if(n < 160){
    for(int ks=0;ks<KSPLIT;ks++) sum += out_acc[((size_t)ks*M_TOT+m)*160 + n];
  }
  float tval = 0.f;
  if(n < 128){
    tval = sum + tok_b[n];
    sA[n] = tval; sB[n] = tval*tval;
  }
  __syncthreads();
  for(int s=64;s>0;s>>=1){
    if(n < s){ sA[n] += sA[n+s]; sB[n] += sB[n+s]; }
    __syncthreads();
  }
  float mean = sA[0]*(1.f/128.f);
  float var  = sB[0]*(1.f/128.f) - mean*mean;
  float rstd = rsqrtf(var + 1e-5f);
  if(n<128){
    out[TOK_OFF + (size_t)m*128 + n] = (tval-mean)*rstd*ln_g[n] + ln_b[n];
  } else if(n<160){
    out[AUX_OFF + (size_t)m*32 + (n-128)] = sum + aux_b[n-128];
  } else if(n<163){
    int j = n-160;
    int pn = m % 343;
    int nz = pn/49, ny=(pn/7)%7, nx=pn%7;
    int g = (j==0)? nz : (j==1)? ny : nx;
    out[CRD_OFF + (size_t)m*3 + j] = (g*8 + 7.5f)*(1.f/63.f);
  }
}

extern "C" void kernel_launch(void* const* d_in, const int* in_sizes, int n_in,
                              void* d_out, int out_size, void* d_ws, size_t ws_size,
                              hipStream_t stream){
  const float* x    = (const float*)d_in[0];
  const float* w1   = (const float*)d_in[1];
  const float* g1   = (const float*)d_in[2];
  const float* b1   = (const float*)d_in[3];
  const float* w2   = (const float*)d_in[4];
  const float* g2   = (const float*)d_in[5];
  const float* b2   = (const float*)d_in[6];
  const float* w3   = (const float*)d_in[7];
  const float* g3   = (const float*)d_in[8];
  const float* b3   = (const float*)d_in[9];
  const float* tokw = (const float*)d_in[10];
  const float* tokb = (const float*)d_in[11];
  const float* auxw = (const float*)d_in[12];
  const float* auxb = (const float*)d_in[13];
  const float* lng  = (const float*)d_in[14];
  const float* lnb  = (const float*)d_in[15];
  float* out = (float*)d_out;

  // ws (256 MiB): y1 [0,128Mi) interleaved, y2 [128Mi,256Mi) interleaved.
  // After conv2, region0 reused: f0 [0,32Mi) channel-major,
  // out_acc [32Mi,+56.2MB).
  char* ws = (char*)d_ws;
  unsigned short* y1u = (unsigned short*)ws;
  unsigned short* y2u = (unsigned short*)(ws + 134217728);
  bf16*  f0      = (bf16*)ws;
  float* out_acc = (float*)(ws + 33554432);
  float* stats   = (float*)d_out;
  float* psum1 = stats;        float* psum2 = stats+2048; float* psum3 = stats+4096;
  float* scsh1 = stats+6144;   float* scsh2 = stats+6208; float* scsh3 = stats+6272;
  unsigned short* wp2 = (unsigned short*)(stats + 8192);
  unsigned short* wp3 = (unsigned short*)(stats + 12288);
  unsigned short* wp1 = (unsigned short*)(stats + 20480);

  hipMemsetAsync(stats, 0, 6144*sizeof(float), stream);

  k_packw<<<86, 256, 0, stream>>>(w1, w2, w3, wp1, wp2, wp3);
  k_conv1<<<4096, 256, 0, stream>>>(x, wp1, y1u, psum1);
  k_finalize<<<1, 64, 0, stream>>>(psum1, g1, b1, scsh1, 16, 1.f/4194304.f);
  k_conv2<<<8192, 256, 0, stream>>>(y1u, wp2, scsh1, y2u, psum2);
  k_finalize<<<1, 64, 0, stream>>>(psum2, g2, b2, scsh2, 16, 1.f/4194304.f);
  k_conv3<<<4096, 256, 0, stream>>>(y2u, wp3, scsh2, f0, psum3);
  k_finalize<<<1, 64, 0, stream>>>(psum3, g3, b3, scsh3, 32, 1.f/524288.f);
  k_gemm<<<1408, 256, 0, stream>>>(f0, tokw, auxw, scsh3, out_acc);
  k_final<<<686, 256, 0, stream>>>(out_acc, tokb, auxb, lng, lnb, out);
}

// Round 10
// 450.072 us; speedup vs baseline: 1.0287x; 1.0287x over previous
//
#include <hip/hip_runtime.h>
#include <hip/hip_bf16.h>

// Geometry (pad=1): conv1/conv2 -> (2,16,128^3), conv3 s2 -> (2,32,64^3).
// y1/y2 voxel-interleaved [b][z][y][x][ic16] (32B/voxel). f0 channel-major.
// Round 20: launch-count diet. k_finalize (x3) and hipMemsetAsync deleted:
// consumers compute BN scale/shift inline from slabbed psums (16-32 threads,
// L2-resident loads, hidden before the existing stage barrier); k_packw
// zeroes psums. 10 -> 6 launches. out_acc relaid m-major ([m][ks][160]) so
// k_final streams one dense 80KB window per block. Hot loops untouched.

typedef __hip_bfloat16 bf16;
typedef __attribute__((ext_vector_type(8))) short short8;   // 8 bf16 = 4 VGPR
typedef __attribute__((ext_vector_type(4))) float f32x4;
__device__ __forceinline__ float b2f(bf16 v){ return __bfloat162float(v); }
__device__ __forceinline__ bf16 f2b(float v){ return __float2bfloat16(v); }
__device__ __forceinline__ unsigned short f2bu(float f){   // RNE
  unsigned u = __float_as_uint(f);
  return (unsigned short)((u + 0x7fff + ((u>>16)&1)) >> 16);
}
__device__ __forceinline__ unsigned cvtpk(float lo, float hi){  // 2xf32 -> 2xbf16 RNE
  unsigned r;
  asm("v_cvt_pk_bf16_f32 %0, %1, %2" : "=v"(r) : "v"(lo), "v"(hi));
  return r;
}

#define SP12 2097152   // 128^3
#define SP3  262144    // 64^3
#define M_TOT 686
#define TOK_OFF 0
#define AUX_OFF 87808
#define CRD_OFF 109760
#define KSPLIT 128
#define NSLAB 32
#define INV_N12 (1.f/4194304.f)
#define INV_N3  (1.f/524288.f)

// ------------- pack conv weights to frag layout + zero psums ----------------
// wp1: [oc16][32]  (k = tap, taps 27..31 = 0)
// wp2: [oc16][448] (k = tap*16+ic, tap 27 = 0)
// wp3: [oc32][h2][224] (k2: tap = (k2>>5)*4 + ((k2>>3)&3), ic = h*8 + (k2&7))
__global__ __launch_bounds__(256) void k_packw(const float* __restrict__ w1,
                                               const float* __restrict__ w2,
                                               const float* __restrict__ w3,
                                               unsigned short* __restrict__ wp1,
                                               unsigned short* __restrict__ wp2,
                                               unsigned short* __restrict__ wp3,
                                               float* __restrict__ stats){
  int i = blockIdx.x*256 + threadIdx.x;   // 22016 items
  if(i < 6144) stats[i] = 0.f;            // psum1/2/3
  if(i < 512){
    int oc = i>>5, k = i&31;
    float v = (k<27)? w1[oc*27+k] : 0.f;
    wp1[i] = f2bu(v);
  } else if(i < 7680){
    int j = i - 512;
    int oc = j/448, k = j - oc*448;
    int tap = k>>4, ic = k&15;
    float v = (tap<27)? w2[(oc*16+ic)*27+tap] : 0.f;
    wp2[oc*448+k] = f2bu(v);
  } else if(i < 22016){
    int j = i - 7680;
    int oc = j/448, r = j - oc*448;
    int h = r/224, k2 = r - h*224;
    int tap = (k2>>5)*4 + ((k2>>3)&3);
    int ic = h*8 + (k2&7);
    float v = (tap<27)? w3[(oc*16+ic)*27+tap] : 0.f;
    wp3[oc*448 + h*224 + k2] = f2bu(v);
  }
}

// ---------------- conv1 (MFMA): (2,1,128^3)->(2,16,128^3), BN1 stats fused --
#define C1P 88
__global__ __launch_bounds__(256) void k_conv1(const float* __restrict__ x,
                                               const unsigned short* __restrict__ wp1,
                                               unsigned short* __restrict__ y1u,
                                               float* __restrict__ psum){
  __shared__ unsigned short in_l[6*6*C1P];   // 6336 B
  int t = threadIdx.x;
  int bx = blockIdx.x;
  int xt = bx&1, yt = (bx>>1)&31, zt = (bx>>6)&31, b = bx>>11;
  int x0 = xt*64, y0 = yt*4, z0 = zt*4;

  for(int i=t; i<648; i+=256){
    int c = i%18; int row = i/18; int yy = row%6; int zz = row/6;
    int gz = z0-1+zz, gy = y0-1+yy;
    bool rowok = ((unsigned)gz<128u) && ((unsigned)gy<128u);
    int gx4 = x0-4+c*4;
    const float* rp = x + (size_t)b*SP12 + (rowok? ((gz<<14)+(gy<<7)) : 0);
    float v0,v1,v2,v3;
    if(rowok && gx4>=0 && gx4<=124){
      float4 v = *(const float4*)(rp + gx4);
      v0=v.x; v1=v.y; v2=v.z; v3=v.w;
    } else {
      float vv[4];
#pragma unroll
      for(int e=0;e<4;e++){
        int gx = gx4+e; bool ok = rowok && ((unsigned)gx<128u);
        float val = rp[ok? gx : 0];
        vv[e] = ok? val : 0.f;
      }
      v0=vv[0]; v1=vv[1]; v2=vv[2]; v3=vv[3];
    }
    uint2 p;
    p.x = cvtpk(v0,v1);
    p.y = cvtpk(v2,v3);
    *(uint2*)&in_l[row*C1P + c*4] = p;
  }
  __syncthreads();

  int lane = t&63, wv = t>>6;
  int m = lane&15, q = lane>>4;
  short8 wfr = *(const short8*)(wp1 + m*32 + q*8);
  int toff[8];
#pragma unroll
  for(int j=0;j<8;j++){
    int tap = q*8+j; if(tap>26) tap=26;
    int dz = tap/9; int rr = tap-dz*9; int dy = rr/3; int dx = rr-dy*3;
    toff[j] = (dz*6+dy)*C1P + dx + 3 + m;
  }
  float s4[4]={0.f,0.f,0.f,0.f}, q4[4]={0.f,0.f,0.f,0.f};
#pragma unroll
  for(int yi=0; yi<4; yi++){
#pragma unroll
    for(int mg=0; mg<4; mg++){
      int base = (wv*6+yi)*C1P + mg*16;
      short8 vf;
#pragma unroll
      for(int j=0;j<8;j++) vf[j] = (short)in_l[base + toff[j]];
      f32x4 acc = (f32x4){0.f,0.f,0.f,0.f};
      acc = __builtin_amdgcn_mfma_f32_16x16x32_bf16(wfr, vf, acc, 0,0,0);
      int gz = z0+wv, gy = y0+yi, gxv = x0 + mg*16 + m;
      size_t vbase = (size_t)((b<<21)|(gz<<14)|(gy<<7)|gxv);
      uint2 pw; pw.x = cvtpk(acc[0],acc[1]); pw.y = cvtpk(acc[2],acc[3]);
      *(uint2*)(y1u + vbase*16 + q*4) = pw;
#pragma unroll
      for(int reg=0; reg<4; reg++){
        float v = acc[reg];
        s4[reg] += v; q4[reg] += v*v;
      }
    }
  }
#pragma unroll
  for(int off=1; off<16; off<<=1){
#pragma unroll
    for(int rg=0;rg<4;rg++){ s4[rg] += __shfl_xor(s4[rg],off); q4[rg] += __shfl_xor(q4[rg],off); }
  }
  __syncthreads();
  float* red = (float*)in_l;
  if(m==0){
#pragma unroll
    for(int rg=0;rg<4;rg++){ red[wv*32 + q*4+rg] = s4[rg]; red[wv*32+16 + q*4+rg] = q4[rg]; }
  }
  __syncthreads();
  if(t<32){
    float tot = red[t]+red[32+t]+red[64+t]+red[96+t];
    atomicAdd(&psum[(blockIdx.x & (NSLAB-1))*64 + t], tot);
  }
}

// ---------------- conv2 (MFMA): interleaved in/out, bn1+relu on stage -------
// r15 z-8 version; BN1 scale/shift computed inline from psum1 (no finalize).
__global__ __launch_bounds__(256) void k_conv2(const unsigned short* __restrict__ y1u,
                                               const unsigned short* __restrict__ wp2,
                                               const float* __restrict__ psum1,
                                               const float* __restrict__ g1,
                                               const float* __restrict__ b1,
                                               unsigned short* __restrict__ y2u,
                                               float* __restrict__ psum2){
  __shared__ unsigned short tile[10*6*18*16];   // 34,560 B
  __shared__ float s_sc[16], s_sh[16];
  int t = threadIdx.x;
  if(t < 16){
    float s=0.f, qv=0.f;
#pragma unroll
    for(int sl=0; sl<NSLAB; sl++){ s += psum1[sl*64+t]; qv += psum1[sl*64+16+t]; }
    float mean = s*INV_N12;
    float var  = qv*INV_N12 - mean*mean;
    float sc = g1[t]*rsqrtf(var+1e-5f);
    s_sc[t] = sc; s_sh[t] = b1[t] - mean*sc;
  }
  int bx = blockIdx.x;
  int txx = bx&7, tyy=(bx>>3)&31, tzz=(bx>>8)&15, b=bx>>12;
  int x0 = txx*16, y0 = tyy*4, z0 = tzz*8;

  // ---- stage ----
  {
    int sxl = t%18, szz = t/18;
    bool sact = t < 180;
    int gx = x0 + sxl - 1, gz = z0 + szz - 1;
    bool szok = sact && ((unsigned)gx<128u) && ((unsigned)gz<128u);
    size_t srow0 = szok ? (size_t)((b<<21)|(gz<<14)|gx) : 0;
    int sw8 = ((sxl>>2)&1)*8;
    int tb = (szz*6*18 + sxl)*16;
    __syncthreads();                      // s_sc ready
    if(sact){
#pragma unroll
      for(int yy=0; yy<6; yy++){
        int gy = y0 + yy - 1;
        bool ok = szok && ((unsigned)gy < 128u);
        uint4 o0; o0.x=0;o0.y=0;o0.z=0;o0.w=0;
        uint4 o1 = o0;
        if(ok){
          const unsigned short* src = y1u + ((srow0 | ((size_t)gy<<7))<<4);
          uint4 u0 = *(const uint4*)src;
          uint4 u1 = *(const uint4*)(src+8);
          unsigned uu[8]; uu[0]=u0.x; uu[1]=u0.y; uu[2]=u0.z; uu[3]=u0.w;
          uu[4]=u1.x; uu[5]=u1.y; uu[6]=u1.z; uu[7]=u1.w;
          unsigned oo[8];
#pragma unroll
          for(int j=0;j<8;j++){
            float lo = fmaxf(__uint_as_float(uu[j]<<16)        *s_sc[2*j]   + s_sh[2*j],   0.f);
            float hi = fmaxf(__uint_as_float(uu[j]&0xffff0000u)*s_sc[2*j+1] + s_sh[2*j+1], 0.f);
            oo[j] = cvtpk(lo, hi);
          }
          o0.x=oo[0]; o0.y=oo[1]; o0.z=oo[2]; o0.w=oo[3];
          o1.x=oo[4]; o1.y=oo[5]; o1.z=oo[6]; o1.w=oo[7];
        }
        unsigned short* dst = &tile[tb + yy*288];
        *(uint4*)(dst + sw8)       = o0;   // h=0 at (0^sw)*8
        *(uint4*)(dst + (8 - sw8)) = o1;   // h=1 at (1^sw)*8
      }
    }
  }
  __syncthreads();

  // ---- compute ----
  int lane = t & 63, wid = t>>6;
  int m = lane & 15, q = lane>>4;
  int qh = q&1, qt = q>>1;
  f32x4 acc[8];
#pragma unroll
  for(int r=0;r<8;r++) acc[r] = (f32x4){0.f,0.f,0.f,0.f};
  const char* tbase = (const char*)tile + wid*6912;
  const unsigned short* wrow = wp2 + m*448 + q*8;
#pragma unroll
  for(int kp=0;kp<14;kp++){
    short8 wf = *(const short8*)(wrow + kp*32);     // A: oc=m
    int tap = kp*2 + qt; if(tap>26) tap=26;
    int dz = tap/9; int rr2 = tap - dz*9; int dy = rr2/3; int dx = rr2 - dy*3;
    int xl = m + dx;
    int abyte = ((dz*6 + dy)*18 + xl)*32 + ((qh ^ ((xl>>2)&1))*16);
    const char* ap = tbase + abyte;
#pragma unroll
    for(int r=0;r<8;r++){
      const short8 vf = *(const short8*)(ap + ((r>>2)*6 + (r&3))*576);
      acc[r] = __builtin_amdgcn_mfma_f32_16x16x32_bf16(wf, vf, acc[r], 0,0,0);
    }
  }

  // ---- epilogue: packed 8B stores + fused BN2 stats ----
  float s4[4]={0.f,0.f,0.f,0.f}, q4[4]={0.f,0.f,0.f,0.f};
#pragma unroll
  for(int r=0;r<8;r++){
    int gz = z0 + wid*2 + (r>>2), gy = y0 + (r&3);
    size_t vbase = (size_t)((b<<21)|(gz<<14)|(gy<<7)|(x0+m));
    uint2 pw; pw.x = cvtpk(acc[r][0],acc[r][1]); pw.y = cvtpk(acc[r][2],acc[r][3]);
    *(uint2*)(y2u + vbase*16 + q*4) = pw;
#pragma unroll
    for(int reg=0;reg<4;reg++){
      float v = acc[r][reg];
      s4[reg] += v; q4[reg] += v*v;
    }
  }
#pragma unroll
  for(int off=1; off<16; off<<=1){
#pragma unroll
    for(int rg=0;rg<4;rg++){ s4[rg] += __shfl_xor(s4[rg],off); q4[rg] += __shfl_xor(q4[rg],off); }
  }
  __syncthreads();
  float* red = (float*)tile;
  if(m==0){
#pragma unroll
    for(int rg=0;rg<4;rg++){ red[wid*32 + q*4+rg] = s4[rg]; red[wid*32+16 + q*4+rg] = q4[rg]; }
  }
  __syncthreads();
  if(t<32){
    float tot = red[t]+red[32+t]+red[64+t]+red[96+t];
    atomicAdd(&psum2[(blockIdx.x & (NSLAB-1))*64 + t], tot);
  }
}

// ---------------- conv3 (MFMA, stride2): interleaved in, channel-major out --
// BN2 scale/shift computed inline from psum2 (no finalize).
#define C3PITCH 576   // bytes per (z,y) row: 36 voxels * 16B
__global__ __launch_bounds__(256) void k_conv3(const unsigned short* __restrict__ y2u,
                                               const unsigned short* __restrict__ wp3,
                                               const float* __restrict__ psum2,
                                               const float* __restrict__ g2,
                                               const float* __restrict__ b2,
                                               bf16* __restrict__ f0,
                                               float* __restrict__ psum3){
  __shared__ unsigned short tile3[45*288];   // 25,920 B
  __shared__ float s_sc[16], s_sh[16];
  int t = threadIdx.x;
  if(t < 16){
    float s=0.f, qv=0.f;
#pragma unroll
    for(int sl=0; sl<NSLAB; sl++){ s += psum2[sl*64+t]; qv += psum2[sl*64+16+t]; }
    float mean = s*INV_N12;
    float var  = qv*INV_N12 - mean*mean;
    float sc = g2[t]*rsqrtf(var+1e-5f);
    s_sc[t] = sc; s_sh[t] = b2[t] - mean*sc;
  }
  int bx = blockIdx.x;
  int tx = bx&3, ty=(bx>>2)&15, tz=(bx>>6)&31, b=bx>>11;
  int x0 = tx*16, y0 = ty*4, z0 = tz*2;
  int gx0 = 2*x0-1, gy0 = 2*y0-1, gz0 = 2*z0-1;

  // stage mapping: t<165 -> (sxl 0..32, szz 0..4), loop yy 0..8
  int sxl = t%33, szz = t/33;
  bool sact = t < 165;
  int gx = gx0+sxl, gz = gz0+szz;
  bool sok = sact && (gx>=0) && (gz>=0);
  int gxc = (sact && gx>=0)? gx : 0;
  int gzc = (sact && gz>=0)? gz : 0;
  const unsigned short* sbase = y2u + (((size_t)((b<<21)|(gzc<<14)|gxc))<<4);
  int sb = (sxl<<4) ^ ((sxl&8)<<1) ^ ((sxl&16)<<1);
  char* sdst = (char*)tile3 + szz*9*C3PITCH + sb;
  unsigned ymask = 0;
#pragma unroll
  for(int yy=0;yy<9;yy++){
    if(sok && (gy0+yy)>=0) ymask |= (1u<<yy);
  }

  __syncthreads();     // s_sc ready

  int lane = t & 63, wid = t>>6;
  int m = lane & 15, q = lane>>4;
  f32x4 acc[2][2];
#pragma unroll
  for(int r=0;r<2;r++){ acc[r][0]=(f32x4){0,0,0,0}; acc[r][1]=(f32x4){0,0,0,0}; }
  const unsigned short* wr0 = wp3 + m*448      + q*8;
  const unsigned short* wr1 = wp3 + (16+m)*448 + q*8;

  // phase A: load full 32B, BN 16ch, store half-0 to LDS, keep half-1 in regs
  uint4 h1[9];
  if(sact){
#pragma unroll
    for(int yy=0;yy<9;yy++){
      int gy = gy0+yy; int gyc = gy<0?0:gy;
      const unsigned short* src = sbase + (size_t)gyc*2048;
      uint4 u0 = *(const uint4*)src;
      uint4 u1 = *(const uint4*)(src+8);
      uint4 o0; o0.x=0;o0.y=0;o0.z=0;o0.w=0;
      uint4 o1 = o0;
      if((ymask>>yy)&1){
        unsigned uu[8]; uu[0]=u0.x; uu[1]=u0.y; uu[2]=u0.z; uu[3]=u0.w;
        uu[4]=u1.x; uu[5]=u1.y; uu[6]=u1.z; uu[7]=u1.w;
        unsigned oo[8];
#pragma unroll
        for(int j=0;j<8;j++){
          float lo = fmaxf(__uint_as_float(uu[j]<<16)        *s_sc[2*j]   + s_sh[2*j],   0.f);
          float hi = fmaxf(__uint_as_float(uu[j]&0xffff0000u)*s_sc[2*j+1] + s_sh[2*j+1], 0.f);
          oo[j] = cvtpk(lo, hi);
        }
        o0.x=oo[0]; o0.y=oo[1]; o0.z=oo[2]; o0.w=oo[3];
        o1.x=oo[4]; o1.y=oo[5]; o1.z=oo[6]; o1.w=oo[7];
      }
      *(uint4*)(sdst + yy*C3PITCH) = o0;
      h1[yy] = o1;
    }
  }

  auto compute = [&](int half){
    const unsigned short* w0h = wr0 + half*224;
    const unsigned short* w1h = wr1 + half*224;
#pragma unroll
    for(int kp=0;kp<7;kp++){
      short8 bf0 = *(const short8*)(w0h + kp*32);
      short8 bf1 = *(const short8*)(w1h + kp*32);
      int tap = kp*4 + q; if(tap>26) tap=26;
      int dz = tap/9; int rr = tap - dz*9; int dy = rr/3; int dx = rr - dy*3;
      int xl = 2*m + dx;
      int sbi = (xl<<4) ^ ((xl&8)<<1) ^ ((xl&16)<<1);
#pragma unroll
      for(int rl=0;rl<2;rl++){
        int row = wid*2 + rl;
        int tz_ = 2*(row>>2) + dz;
        int ty_ = 2*(row&3) + dy;
        const short8 af = *(const short8*)((const char*)tile3 + (tz_*9+ty_)*C3PITCH + sbi);
        acc[rl][0] = __builtin_amdgcn_mfma_f32_16x16x32_bf16(af, bf0, acc[rl][0], 0,0,0);
        acc[rl][1] = __builtin_amdgcn_mfma_f32_16x16x32_bf16(af, bf1, acc[rl][1], 0,0,0);
      }
    }
  };

  __syncthreads();       // half-0 tile ready
  compute(0);
  __syncthreads();       // compute done, tile reusable
  if(sact){
#pragma unroll
    for(int yy=0;yy<9;yy++) *(uint4*)(sdst + yy*C3PITCH) = h1[yy];
  }
  __syncthreads();       // half-1 tile ready
  compute(1);

  float s0=0.f,q0=0.f,s1=0.f,q1=0.f;
#pragma unroll
  for(int rl=0;rl<2;rl++){
    int row = wid*2 + rl;
    int oz = z0 + (row>>2), oy = y0 + (row&3);
    size_t sp = (size_t)oz*4096 + oy*64 + x0 + q*4;
#pragma unroll
    for(int oct=0;oct<2;oct++){
      int oc = oct*16 + m;
      bf16* dst = f0 + (size_t)(b*32+oc)*SP3 + sp;
      f32x4 a = acc[rl][oct];
      uint2 pw; pw.x = cvtpk(a[0],a[1]); pw.y = cvtpk(a[2],a[3]);
      *(uint2*)dst = pw;
#pragma unroll
      for(int reg=0;reg<4;reg++){
        float v = a[reg];
        if(oct==0){ s0 += v; q0 += v*v; } else { s1 += v; q1 += v*v; }
      }
    }
  }
  s0 += __shfl_xor(s0,16); s0 += __shfl_xor(s0,32);
  q0 += __shfl_xor(q0,16); q0 += __shfl_xor(q0,32);
  s1 += __shfl_xor(s1,16); s1 += __shfl_xor(s1,32);
  q1 += __shfl_xor(q1,16); q1 += __shfl_xor(q1,32);
  __syncthreads();
  float* red = (float*)tile3;
  if(lane<16){
    red[wid*64+lane]    = s0; red[wid*64+16+lane] = s1;
    red[wid*64+32+lane] = q0; red[wid*64+48+lane] = q1;
  }
  __syncthreads();
  if(t<64){
    float tot = red[t]+red[64+t]+red[128+t]+red[192+t];
    atomicAdd(&psum3[(blockIdx.x & (NSLAB-1))*64 + t], tot);
  }
}

// ---------------- MFMA projection GEMM: M=686, N=160, K=131072 --------------
// KSPLIT=128; BN3 scale/shift computed inline from psum3 (32-lane reduce).
// out_acc m-major: [m][ks][160]. XCD swizzle: logical=(bid&7)*176+(bid>>3).
__global__ __launch_bounds__(256) void k_gemm(const bf16* __restrict__ f0,
                                              const float* __restrict__ tokw,
                                              const float* __restrict__ auxw,
                                              const float* __restrict__ psum3,
                                              const float* __restrict__ g3,
                                              const float* __restrict__ b3,
                                              float* __restrict__ out_acc){
  __shared__ unsigned short Al[64*72];
  __shared__ unsigned short Wl[160*72];
  __shared__ float g_ss[2];
  int bid = blockIdx.x;
  int logical = (bid & 7)*176 + (bid >> 3);   // 1408 = 8 XCDs * 176
  int ks = logical/11; int mblk = logical - ks*11;
  int M0 = mblk*64;
  int c  = ks >> 2; int kq = ks & 3;
  int t = threadIdx.x;
  if(t < 32){
    float s  = psum3[t*64 + c];
    float qv = psum3[t*64 + 32 + c];
#pragma unroll
    for(int off=16; off>0; off>>=1){ s += __shfl_xor(s,off); qv += __shfl_xor(qv,off); }
    if(t==0){
      float mean = s*INV_N3;
      float var  = qv*INV_N3 - mean*mean;
      float sc = g3[c]*rsqrtf(var+1e-5f);
      g_ss[0] = sc; g_ss[1] = b3[c] - mean*sc;
    }
  }
  __syncthreads();
  float sc = g_ss[0], sh = g_ss[1];
  int lane = t & 63; int wid = t >> 6;
  int wm = (wid & 1)*32; int wn = (wid >> 1)*80;
  f32x4 acc[2][5];
#pragma unroll
  for(int i=0;i<2;i++)
#pragma unroll
    for(int j=0;j<5;j++) acc[i][j] = (f32x4){0.f,0.f,0.f,0.f};

  int ky_off0 = (t&7)>>1, half0 = t&1;
  int m_a = t>>3;
  int mg1 = M0 + m_a;       if(mg1>685) mg1=685;
  int mg2 = M0 + m_a + 32;  if(mg2>685) mg2=685;
  int b1 = mg1/343, r1 = mg1%343;
  int b2 = mg2/343, r2 = mg2%343;
  int sp1 = ((r1/49)*8)*4096 + (((r1/7)%7)*8)*64 + (r1%7)*8;
  int sp2 = ((r2/49)*8)*4096 + (((r2/7)%7)*8)*64 + (r2%7)*8;
  const bf16* f0c1 = f0 + (size_t)(b1*32+c)*SP3;
  const bf16* f0c2 = f0 + (size_t)(b2*32+c)*SP3;

  int wrow_n = t>>3;                 // 0..31 within p-group
  int wkoff  = (t&7)*8;              // 8 floats = 2 float4

  for(int bk=0; bk<16; bk++){
    int bk2 = kq*16 + bk;
    int kz = bk2>>2; int kyb = (bk2&3)*4;
    size_t kbase = (size_t)c*4096 + bk2*64 + wkoff;
    __syncthreads();
#pragma unroll
    for(int p=0;p<5;p++){
      int n = p*32 + wrow_n;
      const float* wsrc = (p<4) ? (tokw + (size_t)n*131072)
                                : (auxw + (size_t)(n-128)*131072);
      float4 v0 = *(const float4*)(wsrc + kbase);
      float4 v1 = *(const float4*)(wsrc + kbase + 4);
      uint4 pw;
      pw.x = cvtpk(v0.x, v0.y); pw.y = cvtpk(v0.z, v0.w);
      pw.z = cvtpk(v1.x, v1.y); pw.w = cvtpk(v1.z, v1.w);
      *(uint4*)&Wl[n*72 + wkoff] = pw;
    }
    {
      int ky = kyb + ky_off0; int xo = half0*8;
      int ldso = ky_off0*16 + half0*8;
      uint4 u1 = *(const uint4*)(f0c1 + sp1 + kz*4096 + ky*64 + xo);
      uint4 u2 = *(const uint4*)(f0c2 + sp2 + kz*4096 + ky*64 + xo);
      unsigned uu[8]; uu[0]=u1.x; uu[1]=u1.y; uu[2]=u1.z; uu[3]=u1.w;
      uu[4]=u2.x; uu[5]=u2.y; uu[6]=u2.z; uu[7]=u2.w;
      unsigned outw[8];
#pragma unroll
      for(int qq=0;qq<8;qq++){
        float lo = fmaxf(__uint_as_float(uu[qq]<<16)*sc + sh, 0.f);
        float hi = fmaxf(__uint_as_float(uu[qq]&0xffff0000u)*sc + sh, 0.f);
        outw[qq] = cvtpk(lo, hi);
      }
      uint4 w1; w1.x=outw[0]; w1.y=outw[1]; w1.z=outw[2]; w1.w=outw[3];
      uint4 w2; w2.x=outw[4]; w2.y=outw[5]; w2.z=outw[6]; w2.w=outw[7];
      *(uint4*)&Al[m_a*72 + ldso] = w1;
      *(uint4*)&Al[(m_a+32)*72 + ldso] = w2;
    }
    __syncthreads();
#pragma unroll
    for(int kstep=0;kstep<2;kstep++){
      int ko = kstep*32 + (lane>>4)*8;
      short8 af[2], bfr[5];
#pragma unroll
      for(int mt=0;mt<2;mt++)
        af[mt] = *(const short8*)&Al[(wm + mt*16 + (lane&15))*72 + ko];
#pragma unroll
      for(int nt=0;nt<5;nt++)
        bfr[nt] = *(const short8*)&Wl[(wn + nt*16 + (lane&15))*72 + ko];
#pragma unroll
      for(int mt=0;mt<2;mt++)
#pragma unroll
        for(int nt=0;nt<5;nt++)
          acc[mt][nt] = __builtin_amdgcn_mfma_f32_16x16x32_bf16(af[mt], bfr[nt], acc[mt][nt], 0,0,0);
    }
  }
#pragma unroll
  for(int mt=0;mt<2;mt++){
    int mb = M0 + wm + mt*16 + (lane>>4)*4;
#pragma unroll
    for(int nt=0;nt<5;nt++){
      int n = wn + nt*16 + (lane&15);
#pragma unroll
      for(int reg=0;reg<4;reg++){
        int mm = mb + reg;
        if(mm < M_TOT)
          out_acc[((size_t)mm*KSPLIT + ks)*160 + n] = acc[mt][nt][reg];
      }
    }
  }
}

// ------------- reduce split-K, +bias, LN(tokens), coords, write out ---------
__global__ __launch_bounds__(256) void k_final(const float* __restrict__ out_acc,
                                               const float* __restrict__ tok_b,
                                               const float* __restrict__ aux_b,
                                               const float* __restrict__ ln_g,
                                               const float* __restrict__ ln_b,
                                               float* __restrict__ out){
  int m = blockIdx.x;            // 0..685
  int n = threadIdx.x;
  __shared__ float sA[128], sB[128];
  float sum = 0.f;
  if(n < 160){
    const float* src = out_acc + (size_t)m*KSPLIT*160 + n;
    for(int ks=0;ks<KSPLIT;ks++) sum += src[ks*160];
  }
  float tval = 0.f;
  if(n < 128){
    tval = sum + tok_b[n];
    sA[n] = tval; sB[n] = tval*tval;
  }
  __syncthreads();
  for(int s=64;s>0;s>>=1){
    if(n < s){ sA[n] += sA[n+s]; sB[n] += sB[n+s]; }
    __syncthreads();
  }
  float mean = sA[0]*(1.f/128.f);
  float var  = sB[0]*(1.f/128.f) - mean*mean;
  float rstd = rsqrtf(var + 1e-5f);
  if(n<128){
    out[TOK_OFF + (size_t)m*128 + n] = (tval-mean)*rstd*ln_g[n] + ln_b[n];
  } else if(n<160){
    out[AUX_OFF + (size_t)m*32 + (n-128)] = sum + aux_b[n-128];
  } else if(n<163){
    int j = n-160;
    int pn = m % 343;
    int nz = pn/49, ny=(pn/7)%7, nx=pn%7;
    int g = (j==0)? nz : (j==1)? ny : nx;
    out[CRD_OFF + (size_t)m*3 + j] = (g*8 + 7.5f)*(1.f/63.f);
  }
}

extern "C" void kernel_launch(void* const* d_in, const int* in_sizes, int n_in,
                              void* d_out, int out_size, void* d_ws, size_t ws_size,
                              hipStream_t stream){
  const float* x    = (const float*)d_in[0];
  const float* w1   = (const float*)d_in[1];
  const float* g1   = (const float*)d_in[2];
  const float* b1   = (const float*)d_in[3];
  const float* w2   = (const float*)d_in[4];
  const float* g2   = (const float*)d_in[5];
  const float* b2   = (const float*)d_in[6];
  const float* w3   = (const float*)d_in[7];
  const float* g3   = (const float*)d_in[8];
  const float* b3   = (const float*)d_in[9];
  const float* tokw = (const float*)d_in[10];
  const float* tokb = (const float*)d_in[11];
  const float* auxw = (const float*)d_in[12];
  const float* auxb = (const float*)d_in[13];
  const float* lng  = (const float*)d_in[14];
  const float* lnb  = (const float*)d_in[15];
  float* out = (float*)d_out;

  // ws (256 MiB): y1 [0,128Mi) interleaved, y2 [128Mi,256Mi) interleaved.
  // After conv2, region0 reused: f0 [0,32Mi) channel-major,
  // out_acc [32Mi,+56.2MB) m-major [m][ks][160].
  char* ws = (char*)d_ws;
  unsigned short* y1u = (unsigned short*)ws;
  unsigned short* y2u = (unsigned short*)(ws + 134217728);
  bf16*  f0      = (bf16*)ws;
  float* out_acc = (float*)(ws + 33554432);
  float* stats   = (float*)d_out;
  float* psum1 = stats;        float* psum2 = stats+2048; float* psum3 = stats+4096;
  unsigned short* wp2 = (unsigned short*)(stats + 8192);
  unsigned short* wp3 = (unsigned short*)(stats + 12288);
  unsigned short* wp1 = (unsigned short*)(stats + 20480);

  k_packw<<<86, 256, 0, stream>>>(w1, w2, w3, wp1, wp2, wp3, stats);
  k_conv1<<<4096, 256, 0, stream>>>(x, wp1, y1u, psum1);
  k_conv2<<<8192, 256, 0, stream>>>(y1u, wp2, psum1, g1, b1, y2u, psum2);
  k_conv3<<<4096, 256, 0, stream>>>(y2u, wp3, psum2, g2, b2, f0, psum3);
  k_gemm<<<1408, 256, 0, stream>>>(f0, tokw, auxw, psum3, g3, b3, out_acc);
  k_final<<<686, 256, 0, stream>>>(out_acc, tokb, auxb, lng, lnb, out);
}